// Round 1
// baseline (627.048 us; speedup 1.0000x reference)
//
#include <hip/hip_runtime.h>
#include <hip/hip_bf16.h>
#include <stdint.h>

#define E_DIM 768
#define S_LEN 2048

typedef __attribute__((ext_vector_type(8))) short short8;   // 8 x bf16 = 4 VGPRs
typedef __attribute__((ext_vector_type(4))) float floatx4;  // MFMA C/D

__device__ inline short f2bf(float f) {
    return __builtin_bit_cast(short, __float2bfloat16(f));
}

__device__ inline floatx4 mfma16(short8 a, short8 b, floatx4 c) {
    return __builtin_amdgcn_mfma_f32_16x16x32_bf16(a, b, c, 0, 0, 0);
}

// ---------------------------------------------------------------------------
// Weight fp32 -> bf16 conversion (scale folds the 1/E score scaling into Wq)
// ---------------------------------------------------------------------------
__global__ void wconv(const float* __restrict__ w, short* __restrict__ o,
                      float scale, int n) {
    int i = blockIdx.x * 256 + threadIdx.x;
    if (i < n) o[i] = f2bf(w[i] * scale);
}

// ---------------------------------------------------------------------------
// Projection GEMM: Y[m,n] = sum_k X[m,k] * W[n,k]   (X fp32, W bf16)
// 128x128 tile, BK=32, 256 threads (4 waves, each 64x64 via 4x4 MFMA tiles).
// LDS XOR-swizzle: 16B unit u of row r stored at r*4 + (u ^ ((r>>1)&3))
//   -> conflict-free ds_read_b128 fragment reads.
// z==0: V projection, written TRANSPOSED  Vt[b][n][s]  (for PV B-fragments)
// z==1: K -> kb[m][n];  z==2: Q -> qb[m][n]
// ---------------------------------------------------------------------------
__global__ __launch_bounds__(256, 3) void proj_gemm(
    const float* __restrict__ Xv, const float* __restrict__ Xk, const float* __restrict__ Xq,
    const short* __restrict__ Wv, const short* __restrict__ Wk, const short* __restrict__ Wq,
    short* __restrict__ Yv, short* __restrict__ Yk, short* __restrict__ Yq)
{
    const int z = blockIdx.z;
    const float* X = (z == 0) ? Xv : (z == 1) ? Xk : Xq;
    const short* W = (z == 0) ? Wv : (z == 1) ? Wk : Wq;
    short*       Y = (z == 0) ? Yv : (z == 1) ? Yk : Yq;

    const int m0 = blockIdx.y * 128;
    const int n0 = blockIdx.x * 128;

    __shared__ short At[128 * 32];
    __shared__ short Bt[128 * 32];

    const int tid  = threadIdx.x;
    const int lane = tid & 63;
    const int wv   = tid >> 6;
    const int lm   = lane & 15, lq = lane >> 4;
    const int wm   = (wv & 1) * 64, wn = (wv >> 1) * 64;

    floatx4 acc[4][4];
#pragma unroll
    for (int i = 0; i < 4; ++i)
#pragma unroll
        for (int j = 0; j < 4; ++j)
            acc[i][j] = (floatx4){0.f, 0.f, 0.f, 0.f};

    for (int kt = 0; kt < E_DIM; kt += 32) {
        // stage A (fp32 -> bf16): 128x32, 4 passes of float4 per thread
#pragma unroll
        for (int p = 0; p < 4; ++p) {
            int g   = p * 256 + tid;          // 0..1023 groups of 4 floats
            int row = g >> 3;
            int c4  = (g & 7) * 4;
            float4 v = *(const float4*)(X + (size_t)(m0 + row) * E_DIM + kt + c4);
            short4 h;
            h.x = f2bf(v.x); h.y = f2bf(v.y); h.z = f2bf(v.z); h.w = f2bf(v.w);
            int u = c4 >> 3, sub = c4 & 7;
            *(short4*)&At[(row * 4 + ((u ^ (row >> 1)) & 3)) * 8 + sub] = h;
        }
        // stage B (bf16 copy): 128x32, 2 passes of 16B per thread
#pragma unroll
        for (int p = 0; p < 2; ++p) {
            int g   = p * 256 + tid;          // 0..511 16B units
            int row = g >> 2, u = g & 3;
            uint4 v = *(const uint4*)(W + (size_t)(n0 + row) * E_DIM + kt + u * 8);
            *(uint4*)&Bt[(row * 4 + ((u ^ (row >> 1)) & 3)) * 8] = v;
        }
        __syncthreads();

        short8 af[4], bf[4];
#pragma unroll
        for (int i = 0; i < 4; ++i) {
            int row = wm + i * 16 + lm;
            af[i] = *(const short8*)&At[(row * 4 + ((lq ^ (row >> 1)) & 3)) * 8];
        }
#pragma unroll
        for (int j = 0; j < 4; ++j) {
            int row = wn + j * 16 + lm;
            bf[j] = *(const short8*)&Bt[(row * 4 + ((lq ^ (row >> 1)) & 3)) * 8];
        }
#pragma unroll
        for (int i = 0; i < 4; ++i)
#pragma unroll
            for (int j = 0; j < 4; ++j)
                acc[i][j] = mfma16(af[i], bf[j], acc[i][j]);
        __syncthreads();
    }

    // epilogue: C/D layout col=lane&15, row=(lane>>4)*4+reg
    if (z == 0) {
#pragma unroll
        for (int i = 0; i < 4; ++i)
#pragma unroll
            for (int r = 0; r < 4; ++r) {
                int m = m0 + wm + i * 16 + lq * 4 + r;
                int bb = m >> 11, s = m & 2047;
#pragma unroll
                for (int j = 0; j < 4; ++j) {
                    int n = n0 + wn + j * 16 + lm;
                    Y[((size_t)bb * E_DIM + n) * S_LEN + s] = f2bf(acc[i][j][r]);
                }
            }
    } else {
#pragma unroll
        for (int i = 0; i < 4; ++i)
#pragma unroll
            for (int r = 0; r < 4; ++r) {
                int m = m0 + wm + i * 16 + lq * 4 + r;
#pragma unroll
                for (int j = 0; j < 4; ++j) {
                    int n = n0 + wn + j * 16 + lm;
                    Y[(size_t)m * E_DIM + n] = f2bf(acc[i][j][r]);
                }
            }
    }
}

// ---------------------------------------------------------------------------
// Flash attention (no-max softmax: |scores| << 1 by construction).
// Block = (q-tile of 64 rows, batch). 512 threads = 8 waves.
// Q tile resident in LDS (96KB, xor-swizzled). K/V fragments read directly
// global->reg (each b128 instruction covers 16 full 64B lines).
// Scores: wave w computes S[32 x 16] slice (rowhalf = w>>2, colslice = w&3).
// P goes through 8KB swizzled LDS; PV: wave w owns output cols [w*96, w*96+96).
// ---------------------------------------------------------------------------
__global__ __launch_bounds__(512, 2) void attn_kernel(
    const short* __restrict__ qb, const short* __restrict__ kb,
    const short* __restrict__ vtb, const int* __restrict__ mask,
    short* __restrict__ aout)
{
    __shared__ short Qs[64 * 768];   // 96 KB
    __shared__ short Ps[64 * 64];    // 8 KB
    __shared__ float rowsum[64];

    const int tid  = threadIdx.x;
    const int lane = tid & 63;
    const int wv   = tid >> 6;             // 0..7
    const int lm   = lane & 15, lq = lane >> 4;
    const int b    = blockIdx.y;
    const int i0   = blockIdx.x * 64;

    if (tid < 64) rowsum[tid] = 0.0f;

    // stage Q tile: 64 x 768 bf16 = 6144 16B-units, xor3 swizzle per row
    const short* qbase = qb + (size_t)(b * S_LEN + i0) * E_DIM;
#pragma unroll
    for (int p = 0; p < 12; ++p) {
        int g   = p * 512 + tid;
        int row = g / 96;
        int u   = g - row * 96;
        uint4 v = *(const uint4*)(qbase + (size_t)row * E_DIM + u * 8);
        *(uint4*)&Qs[(row * 96 + (u ^ (row & 7))) * 8] = v;
    }
    __syncthreads();

    const int cg = wv & 3;    // score col-slice within j-tile
    const int rh = wv >> 2;   // score row-half

    floatx4 oacc[6][4];
#pragma unroll
    for (int c = 0; c < 6; ++c)
#pragma unroll
        for (int t = 0; t < 4; ++t)
            oacc[c][t] = (floatx4){0.f, 0.f, 0.f, 0.f};
    float lsum[2][4];
#pragma unroll
    for (int t = 0; t < 2; ++t)
#pragma unroll
        for (int r = 0; r < 4; ++r) lsum[t][r] = 0.f;

    for (int jt = 0; jt < 32; ++jt) {
        const int j0   = jt * 64;
        const int jcol = j0 + cg * 16 + lm;
        const bool ok  = mask[b * S_LEN + jcol] != 0;
        const short* krow = kb + (size_t)(b * S_LEN + jcol) * E_DIM + lq * 8;

        floatx4 sacc0 = (floatx4){0.f, 0.f, 0.f, 0.f};
        floatx4 sacc1 = (floatx4){0.f, 0.f, 0.f, 0.f};
        const int ra0 = rh * 32 + lm;
        const int ra1 = ra0 + 16;
        const int rx0 = ra0 & 7;        // same for ra1

#pragma unroll
        for (int ks = 0; ks < 24; ++ks) {
            short8 bfrag = {0, 0, 0, 0, 0, 0, 0, 0};
            if (ok) bfrag = *(const short8*)(krow + ks * 32);
            int u = ks * 4 + lq;
            short8 a0 = *(const short8*)&Qs[(ra0 * 96 + (u ^ rx0)) * 8];
            short8 a1 = *(const short8*)&Qs[(ra1 * 96 + (u ^ rx0)) * 8];
            sacc0 = mfma16(a0, bfrag, sacc0);
            sacc1 = mfma16(a1, bfrag, sacc1);
        }

        // exp (no max-subtraction needed), accumulate row sums, write P to LDS
        const int pcol = cg * 16 + lm;
        const int pu   = pcol >> 3;
#pragma unroll
        for (int t = 0; t < 2; ++t) {
            floatx4 sv = t ? sacc1 : sacc0;
#pragma unroll
            for (int r = 0; r < 4; ++r) {
                float p = ok ? __expf(sv[r]) : 0.0f;
                lsum[t][r] += p;
                int prow = rh * 32 + t * 16 + lq * 4 + r;
                Ps[(prow * 8 + (pu ^ (prow & 7))) * 8 + (pcol & 7)] = f2bf(p);
            }
        }
        __syncthreads();

        // PV: oacc[ct][rt] += P[rt-tile] @ V[j-tile, col-slice of this wave]
#pragma unroll
        for (int s2 = 0; s2 < 2; ++s2) {
            short8 pa[4];
#pragma unroll
            for (int rt = 0; rt < 4; ++rt) {
                int prow = rt * 16 + lm;
                int u    = s2 * 4 + lq;
                pa[rt] = *(const short8*)&Ps[(prow * 8 + (u ^ (prow & 7))) * 8];
            }
#pragma unroll
            for (int ct = 0; ct < 6; ++ct) {
                int col = wv * 96 + ct * 16 + lm;
                short8 vfrag = *(const short8*)(vtb + ((size_t)b * E_DIM + col) * S_LEN
                                                + j0 + s2 * 32 + lq * 8);
#pragma unroll
                for (int rt = 0; rt < 4; ++rt)
                    oacc[ct][rt] = mfma16(pa[rt], vfrag, oacc[ct][rt]);
            }
        }
        __syncthreads();
    }

    // reduce row sums: shfl over the 16 lanes sharing a row, then LDS atomics
#pragma unroll
    for (int t = 0; t < 2; ++t)
#pragma unroll
        for (int r = 0; r < 4; ++r) {
            float v = lsum[t][r];
            v += __shfl_xor(v, 1);
            v += __shfl_xor(v, 2);
            v += __shfl_xor(v, 4);
            v += __shfl_xor(v, 8);
            if (lm == 0) atomicAdd(&rowsum[rh * 32 + t * 16 + lq * 4 + r], v);
        }
    __syncthreads();

    short* obase = aout + (size_t)(b * S_LEN + i0) * E_DIM;
#pragma unroll
    for (int ct = 0; ct < 6; ++ct) {
        int col = wv * 96 + ct * 16 + lm;
#pragma unroll
        for (int rt = 0; rt < 4; ++rt)
#pragma unroll
            for (int r = 0; r < 4; ++r) {
                int row = rt * 16 + lq * 4 + r;
                float o = oacc[ct][rt][r] / rowsum[row];
                obase[(size_t)row * E_DIM + col] = f2bf(o);
            }
    }
}

// ---------------------------------------------------------------------------
// Output GEMM: out[m,n] = sum_k A[m,k] * Wo[n,k] + bo[n]   (A bf16, out fp32)
// ---------------------------------------------------------------------------
__global__ __launch_bounds__(256, 3) void out_gemm(
    const short* __restrict__ A, const short* __restrict__ W,
    const float* __restrict__ bias, float* __restrict__ Y)
{
    const int m0 = blockIdx.y * 128;
    const int n0 = blockIdx.x * 128;

    __shared__ short At[128 * 32];
    __shared__ short Bt[128 * 32];

    const int tid  = threadIdx.x;
    const int lane = tid & 63;
    const int wv   = tid >> 6;
    const int lm   = lane & 15, lq = lane >> 4;
    const int wm   = (wv & 1) * 64, wn = (wv >> 1) * 64;

    floatx4 acc[4][4];
#pragma unroll
    for (int i = 0; i < 4; ++i)
#pragma unroll
        for (int j = 0; j < 4; ++j)
            acc[i][j] = (floatx4){0.f, 0.f, 0.f, 0.f};

    for (int kt = 0; kt < E_DIM; kt += 32) {
#pragma unroll
        for (int p = 0; p < 2; ++p) {
            int g   = p * 256 + tid;
            int row = g >> 2, u = g & 3;
            uint4 v = *(const uint4*)(A + (size_t)(m0 + row) * E_DIM + kt + u * 8);
            *(uint4*)&At[(row * 4 + ((u ^ (row >> 1)) & 3)) * 8] = v;
        }
#pragma unroll
        for (int p = 0; p < 2; ++p) {
            int g   = p * 256 + tid;
            int row = g >> 2, u = g & 3;
            uint4 v = *(const uint4*)(W + (size_t)(n0 + row) * E_DIM + kt + u * 8);
            *(uint4*)&Bt[(row * 4 + ((u ^ (row >> 1)) & 3)) * 8] = v;
        }
        __syncthreads();

        short8 af[4], bf[4];
#pragma unroll
        for (int i = 0; i < 4; ++i) {
            int row = wm + i * 16 + lm;
            af[i] = *(const short8*)&At[(row * 4 + ((lq ^ (row >> 1)) & 3)) * 8];
        }
#pragma unroll
        for (int j = 0; j < 4; ++j) {
            int row = wn + j * 16 + lm;
            bf[j] = *(const short8*)&Bt[(row * 4 + ((lq ^ (row >> 1)) & 3)) * 8];
        }
#pragma unroll
        for (int i = 0; i < 4; ++i)
#pragma unroll
            for (int j = 0; j < 4; ++j)
                acc[i][j] = mfma16(af[i], bf[j], acc[i][j]);
        __syncthreads();
    }

#pragma unroll
    for (int j = 0; j < 4; ++j) {
        int n = n0 + wn + j * 16 + lm;
        float bv = bias[n];
#pragma unroll
        for (int i = 0; i < 4; ++i)
#pragma unroll
            for (int r = 0; r < 4; ++r) {
                int m = m0 + wm + i * 16 + lq * 4 + r;
                Y[(size_t)m * E_DIM + n] = acc[i][j][r] + bv;
            }
    }
}

// ---------------------------------------------------------------------------
extern "C" void kernel_launch(void* const* d_in, const int* in_sizes, int n_in,
                              void* d_out, int out_size, void* d_ws, size_t ws_size,
                              hipStream_t stream) {
    const float* value = (const float*)d_in[0];
    const float* key   = (const float*)d_in[1];
    const float* query = (const float*)d_in[2];
    const int*   mask  = (const int*)d_in[3];
    const float* Wv    = (const float*)d_in[4];
    const float* Wk    = (const float*)d_in[5];
    const float* Wq    = (const float*)d_in[6];
    const float* Wo    = (const float*)d_in[7];
    const float* bo    = (const float*)d_in[8];
    float* out = (float*)d_out;

    const int WN = E_DIM * E_DIM;          // 589824
    const size_t ACT = (size_t)8 * S_LEN * E_DIM; // 12582912 elements

    short* Wvb   = (short*)d_ws;
    short* Wkb   = Wvb + WN;
    short* Wqb   = Wkb + WN;
    short* Wob   = Wqb + WN;
    short* qbuf  = Wob + WN;
    short* kbuf  = qbuf + ACT;
    short* vtbuf = kbuf + ACT;     // V stored transposed per batch: [b][e][s]
    short* abuf  = vtbuf + ACT;    // attention output, bf16 [b*s][e]

    wconv<<<2304, 256, 0, stream>>>(Wv, Wvb, 1.0f, WN);
    wconv<<<2304, 256, 0, stream>>>(Wk, Wkb, 1.0f, WN);
    wconv<<<2304, 256, 0, stream>>>(Wq, Wqb, 1.0f / (float)E_DIM, WN); // fold 1/E
    wconv<<<2304, 256, 0, stream>>>(Wo, Wob, 1.0f, WN);

    proj_gemm<<<dim3(6, 128, 3), 256, 0, stream>>>(
        value, key, query, Wvb, Wkb, Wqb, vtbuf, kbuf, qbuf);

    attn_kernel<<<dim3(32, 8), 512, 0, stream>>>(qbuf, kbuf, vtbuf, mask, abuf);

    out_gemm<<<dim3(6, 128), 256, 0, stream>>>(abuf, Wob, bo, out);
}

// Round 2
// 457.127 us; speedup vs baseline: 1.3717x; 1.3717x over previous
//
#include <hip/hip_runtime.h>
#include <hip/hip_bf16.h>
#include <stdint.h>

#define E_DIM 768
#define S_LEN 2048
#define BATCH 8

typedef __attribute__((ext_vector_type(8))) short short8;   // 8 x bf16 = 4 VGPRs
typedef __attribute__((ext_vector_type(4))) float floatx4;  // MFMA C/D

__device__ __forceinline__ short f2bf(float f) {
    return __builtin_bit_cast(short, __float2bfloat16(f));
}

__device__ __forceinline__ floatx4 mfma16(short8 a, short8 b, floatx4 c) {
    return __builtin_amdgcn_mfma_f32_16x16x32_bf16(a, b, c, 0, 0, 0);
}

// async global->LDS, 16B per lane. LDS side is wave-uniform base + lane*16;
// global side is per-lane free -> we permute the SOURCE to realize an XOR
// swizzle in LDS without breaking the lane*16 constraint.
__device__ __forceinline__ void glds16(const short* g, short* l) {
    __builtin_amdgcn_global_load_lds(
        (const __attribute__((address_space(1))) void*)g,
        (__attribute__((address_space(3))) void*)l,
        16, 0, 0);
}

// ---------------------------------------------------------------------------
// Shared GEMM core: C[128x128] += A[128xK] * B[128xK]^T   (both row-major, K
// contiguous, row stride == K). 256 threads = 4 waves in 2x2; each wave does
// a 64x64 tile as 4x4 frags of 16x16x32 bf16 MFMA. BK=64, single-buffered.
//
// Staging: 16 glds16 per tile per operand (1KB chunks of 8 rows). Within a
// chunk, lane (rl=lane>>3, sl=lane&7) fetches global 16B-unit u = sl^rl of
// row rl -> LDS holds unit u of row r at chunk + ((r&7)*8 + (u^(r&7)))*16B.
// Fragment reads (ds_read_b128) then hit 8 distinct bank-quads per 8-lane
// group -> conflict-free.
// ---------------------------------------------------------------------------
__device__ __forceinline__ void gemm_core(
    const short* __restrict__ Abase,   // tile row 0, k 0
    const short* __restrict__ Bbase,
    int K,
    short* At, short* Bt,              // 128*64 shorts each (16KB)
    floatx4 acc[4][4])
{
    const int tid  = threadIdx.x;
    const int lane = tid & 63;
    const int wv   = tid >> 6;
    const int lm   = lane & 15, lq = lane >> 4;
    const int rl   = lane >> 3, sl = lane & 7;
    const int usw  = sl ^ rl;                   // swizzled source unit
    const int wm   = (wv & 1) * 64, wn = (wv >> 1) * 64;

    // per-lane global bases for this wave's 32 staging rows (4 chunks of 8)
    const short* ag = Abase + (size_t)(wv * 32 + rl) * K + usw * 8;
    const short* bg = Bbase + (size_t)(wv * 32 + rl) * K + usw * 8;
    short* al = At + wv * 4 * 512;              // 4 chunks x 512 shorts
    short* bl = Bt + wv * 4 * 512;
    const size_t rowskip = (size_t)8 * K;       // 8 rows per chunk

    for (int kt = 0; kt < K; kt += 64) {
#pragma unroll
        for (int c = 0; c < 4; ++c) glds16(ag + c * rowskip + kt, al + c * 512);
#pragma unroll
        for (int c = 0; c < 4; ++c) glds16(bg + c * rowskip + kt, bl + c * 512);
        __syncthreads();   // drains vmcnt -> staging visible

#pragma unroll
        for (int s = 0; s < 2; ++s) {
            const int u = s * 4 + lq;
            short8 af[4], bf[4];
#pragma unroll
            for (int i = 0; i < 4; ++i) {
                int r = wm + i * 16 + lm;
                af[i] = *(const short8*)&At[((r >> 3) * 64 + (r & 7) * 8 + (u ^ (r & 7))) * 8];
            }
#pragma unroll
            for (int j = 0; j < 4; ++j) {
                int r = wn + j * 16 + lm;
                bf[j] = *(const short8*)&Bt[((r >> 3) * 64 + (r & 7) * 8 + (u ^ (r & 7))) * 8];
            }
#pragma unroll
            for (int i = 0; i < 4; ++i)
#pragma unroll
                for (int j = 0; j < 4; ++j)
                    acc[i][j] = mfma16(af[i], bf[j], acc[i][j]);
        }
        __syncthreads();   // protect LDS before next overwrite
    }
}

// ---------------------------------------------------------------------------
// fp32 -> bf16 converts
// ---------------------------------------------------------------------------
__global__ void convert_acts(const float* __restrict__ v, const float* __restrict__ k,
                             const float* __restrict__ q,
                             short* __restrict__ xv, short* __restrict__ xk,
                             short* __restrict__ xq) {
    const int z = blockIdx.y;
    const float* src = (z == 0) ? v : (z == 1) ? k : q;
    short* dst = (z == 0) ? xv : (z == 1) ? xk : xq;
    size_t i = ((size_t)blockIdx.x * 256 + threadIdx.x) * 4;
    float4 f = *(const float4*)(src + i);
    short4 h;
    h.x = f2bf(f.x); h.y = f2bf(f.y); h.z = f2bf(f.z); h.w = f2bf(f.w);
    *(short4*)(dst + i) = h;
}

__global__ void convert_wts(const float* __restrict__ wv, const float* __restrict__ wk,
                            const float* __restrict__ wq, const float* __restrict__ wo,
                            short* __restrict__ o) {
    const int z = blockIdx.y;
    const float* src = (z == 0) ? wv : (z == 1) ? wk : (z == 2) ? wq : wo;
    const float scale = (z == 2) ? (1.0f / (float)E_DIM) : 1.0f;  // fold 1/E into Wq
    size_t i = ((size_t)blockIdx.x * 256 + threadIdx.x) * 4;
    float4 f = *(const float4*)(src + i);
    short4 h;
    h.x = f2bf(f.x * scale); h.y = f2bf(f.y * scale);
    h.z = f2bf(f.z * scale); h.w = f2bf(f.w * scale);
    *(short4*)(o + (size_t)z * E_DIM * E_DIM + i) = h;
}

// ---------------------------------------------------------------------------
// Projection GEMMs: Y[m,n] = X[m,:] . W[n,:]   (all bf16)
// z==0: V, stored transposed vt[b][n][s]; z==1: K; z==2: Q (Wq pre-scaled)
// ---------------------------------------------------------------------------
__global__ __launch_bounds__(256, 3) void proj_kernel(
    const short* __restrict__ xv, const short* __restrict__ xk, const short* __restrict__ xq,
    const short* __restrict__ Wb,
    short* __restrict__ Yv, short* __restrict__ Yk, short* __restrict__ Yq)
{
    const int z = blockIdx.z;
    const short* X = (z == 0) ? xv : (z == 1) ? xk : xq;
    const short* W = Wb + (size_t)z * E_DIM * E_DIM;
    short*       Y = (z == 0) ? Yv : (z == 1) ? Yk : Yq;

    const int m0 = blockIdx.y * 128;
    const int n0 = blockIdx.x * 128;

    __shared__ short At[128 * 64];
    __shared__ short Bt[128 * 64];

    floatx4 acc[4][4];
#pragma unroll
    for (int i = 0; i < 4; ++i)
#pragma unroll
        for (int j = 0; j < 4; ++j) acc[i][j] = (floatx4){0.f, 0.f, 0.f, 0.f};

    gemm_core(X + (size_t)m0 * E_DIM, W + (size_t)n0 * E_DIM, E_DIM, At, Bt, acc);

    const int lane = threadIdx.x & 63, wv = threadIdx.x >> 6;
    const int lm = lane & 15, lq = lane >> 4;
    const int wm = (wv & 1) * 64, wn = (wv >> 1) * 64;

    if (z == 0) {   // V transposed: vt[b][n][s]
#pragma unroll
        for (int i = 0; i < 4; ++i)
#pragma unroll
            for (int r = 0; r < 4; ++r) {
                int m = m0 + wm + i * 16 + lq * 4 + r;
                int bb = m >> 11, s = m & 2047;
#pragma unroll
                for (int j = 0; j < 4; ++j) {
                    int n = n0 + wn + j * 16 + lm;
                    Y[((size_t)bb * E_DIM + n) * S_LEN + s] = f2bf(acc[i][j][r]);
                }
            }
    } else {
#pragma unroll
        for (int i = 0; i < 4; ++i)
#pragma unroll
            for (int r = 0; r < 4; ++r) {
                int m = m0 + wm + i * 16 + lq * 4 + r;
#pragma unroll
                for (int j = 0; j < 4; ++j) {
                    int n = n0 + wn + j * 16 + lm;
                    Y[(size_t)m * E_DIM + n] = f2bf(acc[i][j][r]);
                }
            }
    }
}

// ---------------------------------------------------------------------------
// Pass 1: S = q . k^T, fused mask + exp (no max needed: |s| < 0.5 by
// construction since 1/E is folded into Wq), P bf16 out, rowsum atomics.
// ---------------------------------------------------------------------------
__global__ __launch_bounds__(256, 3) void score_kernel(
    const short* __restrict__ qb, const short* __restrict__ kb,
    const int* __restrict__ mask,
    short* __restrict__ P, float* __restrict__ rowsum)
{
    const int b  = blockIdx.z;
    const int m0 = blockIdx.y * 128;
    const int n0 = blockIdx.x * 128;

    __shared__ short At[128 * 64];
    __shared__ short Bt[128 * 64];

    floatx4 acc[4][4];
#pragma unroll
    for (int i = 0; i < 4; ++i)
#pragma unroll
        for (int j = 0; j < 4; ++j) acc[i][j] = (floatx4){0.f, 0.f, 0.f, 0.f};

    gemm_core(qb + ((size_t)b * S_LEN + m0) * E_DIM,
              kb + ((size_t)b * S_LEN + n0) * E_DIM, E_DIM, At, Bt, acc);

    const int lane = threadIdx.x & 63, wv = threadIdx.x >> 6;
    const int lm = lane & 15, lq = lane >> 4;
    const int wm = (wv & 1) * 64, wn = (wv >> 1) * 64;

    float rsum[4][4];
#pragma unroll
    for (int i = 0; i < 4; ++i)
#pragma unroll
        for (int r = 0; r < 4; ++r) rsum[i][r] = 0.f;

    const size_t Pbb = (size_t)b * S_LEN * S_LEN;
#pragma unroll
    for (int j = 0; j < 4; ++j) {
        int n = n0 + wn + j * 16 + lm;
        int mv = mask[b * S_LEN + n];
#pragma unroll
        for (int i = 0; i < 4; ++i) {
            int mbase = m0 + wm + i * 16 + lq * 4;
#pragma unroll
            for (int r = 0; r < 4; ++r) {
                float p = mv ? __expf(acc[i][j][r]) : 0.0f;
                rsum[i][r] += p;
                P[Pbb + (size_t)(mbase + r) * S_LEN + n] = f2bf(p);
            }
        }
    }
#pragma unroll
    for (int i = 0; i < 4; ++i)
#pragma unroll
        for (int r = 0; r < 4; ++r) {
            float v = rsum[i][r];
            v += __shfl_xor(v, 1);
            v += __shfl_xor(v, 2);
            v += __shfl_xor(v, 4);
            v += __shfl_xor(v, 8);
            if (lm == 0)
                atomicAdd(&rowsum[b * S_LEN + m0 + wm + i * 16 + lq * 4 + r], v);
        }
}

// ---------------------------------------------------------------------------
// Pass 2: O = (P . V) / rowsum   -> abuf bf16.  B operand is vt[b][e][s].
// ---------------------------------------------------------------------------
__global__ __launch_bounds__(256, 3) void pv_kernel(
    const short* __restrict__ P, const short* __restrict__ vt,
    const float* __restrict__ rowsum, short* __restrict__ abuf)
{
    const int b  = blockIdx.z;
    const int m0 = blockIdx.y * 128;
    const int n0 = blockIdx.x * 128;

    __shared__ short At[128 * 64];
    __shared__ short Bt[128 * 64];

    floatx4 acc[4][4];
#pragma unroll
    for (int i = 0; i < 4; ++i)
#pragma unroll
        for (int j = 0; j < 4; ++j) acc[i][j] = (floatx4){0.f, 0.f, 0.f, 0.f};

    gemm_core(P + ((size_t)b * S_LEN + m0) * S_LEN,
              vt + ((size_t)b * E_DIM + n0) * S_LEN, S_LEN, At, Bt, acc);

    const int lane = threadIdx.x & 63, wv = threadIdx.x >> 6;
    const int lm = lane & 15, lq = lane >> 4;
    const int wm = (wv & 1) * 64, wn = (wv >> 1) * 64;

#pragma unroll
    for (int i = 0; i < 4; ++i) {
        int mbase = m0 + wm + i * 16 + lq * 4;
#pragma unroll
        for (int r = 0; r < 4; ++r) {
            float inv = 1.0f / rowsum[b * S_LEN + mbase + r];
            size_t ob = ((size_t)b * S_LEN + mbase + r) * E_DIM;
#pragma unroll
            for (int j = 0; j < 4; ++j) {
                int n = n0 + wn + j * 16 + lm;
                abuf[ob + n] = f2bf(acc[i][j][r] * inv);
            }
        }
    }
}

// ---------------------------------------------------------------------------
// Output GEMM: out[m,n] = A[m,:] . Wo[n,:] + bo[n]   (fp32 out)
// ---------------------------------------------------------------------------
__global__ __launch_bounds__(256, 3) void out_kernel(
    const short* __restrict__ A, const short* __restrict__ W,
    const float* __restrict__ bias, float* __restrict__ Y)
{
    const int m0 = blockIdx.y * 128;
    const int n0 = blockIdx.x * 128;

    __shared__ short At[128 * 64];
    __shared__ short Bt[128 * 64];

    floatx4 acc[4][4];
#pragma unroll
    for (int i = 0; i < 4; ++i)
#pragma unroll
        for (int j = 0; j < 4; ++j) acc[i][j] = (floatx4){0.f, 0.f, 0.f, 0.f};

    gemm_core(A + (size_t)m0 * E_DIM, W + (size_t)n0 * E_DIM, E_DIM, At, Bt, acc);

    const int lane = threadIdx.x & 63, wv = threadIdx.x >> 6;
    const int lm = lane & 15, lq = lane >> 4;
    const int wm = (wv & 1) * 64, wn = (wv >> 1) * 64;

#pragma unroll
    for (int j = 0; j < 4; ++j) {
        int n = n0 + wn + j * 16 + lm;
        float bv = bias[n];
#pragma unroll
        for (int i = 0; i < 4; ++i)
#pragma unroll
            for (int r = 0; r < 4; ++r) {
                int m = m0 + wm + i * 16 + lq * 4 + r;
                Y[(size_t)m * E_DIM + n] = acc[i][j][r] + bv;
            }
    }
}

// ---------------------------------------------------------------------------
extern "C" void kernel_launch(void* const* d_in, const int* in_sizes, int n_in,
                              void* d_out, int out_size, void* d_ws, size_t ws_size,
                              hipStream_t stream) {
    const float* value = (const float*)d_in[0];
    const float* key   = (const float*)d_in[1];
    const float* query = (const float*)d_in[2];
    const int*   mask  = (const int*)d_in[3];
    const float* Wv    = (const float*)d_in[4];
    const float* Wk    = (const float*)d_in[5];
    const float* Wq    = (const float*)d_in[6];
    const float* Wo    = (const float*)d_in[7];
    const float* bo    = (const float*)d_in[8];
    float* out = (float*)d_out;

    const size_t WN  = (size_t)E_DIM * E_DIM;            // 589824
    const size_t ACT = (size_t)BATCH * S_LEN * E_DIM;    // 12582912

    // ws layout (shorts). P overlays dead xv/xk; abuf overlays dead qb.
    short* Wb  = (short*)d_ws;         // 4 weights: Wv,Wk,Wq(scaled),Wo
    short* xv  = Wb + 4 * WN;          // region1: 3*ACT
    short* xk  = xv + ACT;
    short* xq  = xk + ACT;
    short* vt  = xq + ACT;             // region2: 3*ACT
    short* kb  = vt + ACT;
    short* qb  = kb + ACT;
    float* rowsum = (float*)(qb + ACT);                  // 16384 floats
    short* P    = xv;                  // 8*2048*2048 = 33554432 <= 3*ACT
    short* abuf = qb;                  // == ACT

    hipMemsetAsync(rowsum, 0, (size_t)BATCH * S_LEN * sizeof(float), stream);

    convert_wts<<<dim3(576, 4), 256, 0, stream>>>(Wv, Wk, Wq, Wo, Wb);
    convert_acts<<<dim3(12288, 3), 256, 0, stream>>>(value, key, query, xv, xk, xq);

    proj_kernel<<<dim3(6, 128, 3), 256, 0, stream>>>(xv, xk, xq, Wb, vt, kb, qb);

    score_kernel<<<dim3(16, 16, 8), 256, 0, stream>>>(qb, kb, mask, P, rowsum);

    pv_kernel<<<dim3(6, 16, 8), 256, 0, stream>>>(P, vt, rowsum, abuf);

    out_kernel<<<dim3(6, 128), 256, 0, stream>>>(abuf, Wb + 3 * WN, bo, out);
}

// Round 3
// 347.333 us; speedup vs baseline: 1.8053x; 1.3161x over previous
//
#include <hip/hip_runtime.h>
#include <hip/hip_bf16.h>
#include <stdint.h>

#define E_DIM 768
#define S_LEN 2048
#define BATCH 8

typedef __attribute__((ext_vector_type(8))) short short8;   // 8 x bf16 = 4 VGPRs
typedef __attribute__((ext_vector_type(4))) float floatx4;  // MFMA C/D

__device__ __forceinline__ short f2bf(float f) {
    return __builtin_bit_cast(short, __float2bfloat16(f));
}

__device__ __forceinline__ floatx4 mfma16(short8 a, short8 b, floatx4 c) {
    return __builtin_amdgcn_mfma_f32_16x16x32_bf16(a, b, c, 0, 0, 0);
}

// async global->LDS, 16B per lane; LDS dst is wave-uniform base + lane*16,
// global src per-lane free -> XOR swizzle realized by permuting the SOURCE.
__device__ __forceinline__ void glds16(const short* g, short* l) {
    __builtin_amdgcn_global_load_lds(
        (const __attribute__((address_space(1))) void*)g,
        (__attribute__((address_space(3))) void*)l,
        16, 0, 0);
}

// ---------------------------------------------------------------------------
// Shared GEMM core: C[128x128] += A[128xK] * B[128xK]^T, row strides sA/sB.
// 256 threads = 4 waves (2x2), each wave 64x64 via 4x4 frags of 16x16x32.
// BK=64 single-buffered; staging in 1KB chunks of 8 rows with XOR-swizzled
// source units -> conflict-free ds_read_b128 fragment reads (verified R2:
// SQ_LDS_BANK_CONFLICT == 0).
// ---------------------------------------------------------------------------
__device__ __forceinline__ void gemm_core(
    const short* __restrict__ Abase, size_t sA,
    const short* __restrict__ Bbase, size_t sB,
    int K,
    short* At, short* Bt,              // 128*64 shorts each (16KB)
    floatx4 acc[4][4])
{
    const int tid  = threadIdx.x;
    const int lane = tid & 63;
    const int wv   = tid >> 6;
    const int lm   = lane & 15, lq = lane >> 4;
    const int rl   = lane >> 3, sl = lane & 7;
    const int usw  = sl ^ rl;                   // swizzled source unit
    const int wm   = (wv & 1) * 64, wn = (wv >> 1) * 64;

    const short* ag = Abase + (size_t)(wv * 32 + rl) * sA + usw * 8;
    const short* bg = Bbase + (size_t)(wv * 32 + rl) * sB + usw * 8;
    short* al = At + wv * 4 * 512;
    short* bl = Bt + wv * 4 * 512;
    const size_t askip = 8 * sA, bskip = 8 * sB;

    for (int kt = 0; kt < K; kt += 64) {
#pragma unroll
        for (int c = 0; c < 4; ++c) glds16(ag + c * askip + kt, al + c * 512);
#pragma unroll
        for (int c = 0; c < 4; ++c) glds16(bg + c * bskip + kt, bl + c * 512);
        __syncthreads();

#pragma unroll
        for (int s = 0; s < 2; ++s) {
            const int u = s * 4 + lq;
            short8 af[4], bf[4];
#pragma unroll
            for (int i = 0; i < 4; ++i) {
                int r = wm + i * 16 + lm;
                af[i] = *(const short8*)&At[((r >> 3) * 64 + (r & 7) * 8 + (u ^ (r & 7))) * 8];
            }
#pragma unroll
            for (int j = 0; j < 4; ++j) {
                int r = wn + j * 16 + lm;
                bf[j] = *(const short8*)&Bt[((r >> 3) * 64 + (r & 7) * 8 + (u ^ (r & 7))) * 8];
            }
#pragma unroll
            for (int i = 0; i < 4; ++i)
#pragma unroll
                for (int j = 0; j < 4; ++j)
                    acc[i][j] = mfma16(af[i], bf[j], acc[i][j]);
        }
        __syncthreads();
    }
}

// ---------------------------------------------------------------------------
// Per-batch mask compaction: jidx[b][0..nv) = valid column indices,
// [nv..2048) = 0 (finite dup), nvp = nv rounded up to 128 (min 128).
// ---------------------------------------------------------------------------
__global__ void mask_scan(const int* __restrict__ mask, int* __restrict__ jidx,
                          int* __restrict__ nv, int* __restrict__ nvp) {
    const int b = blockIdx.x;
    const int t = threadIdx.x;
    __shared__ int cnt[256];
    int m[8];
    int c = 0;
#pragma unroll
    for (int k = 0; k < 8; ++k) {
        m[k] = mask[b * S_LEN + t * 8 + k];
        c += (m[k] != 0);
    }
    cnt[t] = c;
    __syncthreads();
    for (int off = 1; off < 256; off <<= 1) {
        int v = (t >= off) ? cnt[t - off] : 0;
        __syncthreads();
        cnt[t] += v;
        __syncthreads();
    }
    int pos = cnt[t] - c;   // exclusive prefix
    const int total = cnt[255];
#pragma unroll
    for (int k = 0; k < 8; ++k)
        if (m[k] != 0) jidx[b * S_LEN + (pos++)] = t * 8 + k;
    __syncthreads();
    for (int i = total + t; i < S_LEN; i += 256) jidx[b * S_LEN + i] = 0;
    if (t == 0) {
        nv[b] = total;
        int p = (total + 127) & ~127;
        if (p < 128) p = 128;
        nvp[b] = p;
    }
}

// ---------------------------------------------------------------------------
// fp32 -> bf16; z==0/1 gather value/key rows through jidx (compacted), z==2
// straight copy of query. 4 rows per block.
// ---------------------------------------------------------------------------
__global__ void convert_gather(const float* __restrict__ v, const float* __restrict__ k,
                               const float* __restrict__ q,
                               const int* __restrict__ jidx, const int* __restrict__ nvp,
                               short* __restrict__ xv, short* __restrict__ xk,
                               short* __restrict__ xq) {
    const int z = blockIdx.y, b = blockIdx.z;
    const int r0 = blockIdx.x * 4;
    if (z < 2 && r0 >= nvp[b]) return;
    const float* src = (z == 0) ? v : (z == 1) ? k : q;
    short* dst = (z == 0) ? xv : (z == 1) ? xk : xq;
    const int tid = threadIdx.x;
#pragma unroll
    for (int p = 0; p < 3; ++p) {
        int g   = p * 256 + tid;          // 0..767 float4 units
        int row = r0 + g / 192;
        int c4  = (g % 192) * 4;
        int srow = (z == 2) ? row : jidx[b * S_LEN + row];
        float4 f = *(const float4*)(src + ((size_t)b * S_LEN + srow) * E_DIM + c4);
        short4 h;
        h.x = f2bf(f.x); h.y = f2bf(f.y); h.z = f2bf(f.z); h.w = f2bf(f.w);
        *(short4*)(dst + ((size_t)b * S_LEN + row) * E_DIM + c4) = h;
    }
}

__global__ void convert_wts(const float* __restrict__ wv, const float* __restrict__ wk,
                            const float* __restrict__ wq, const float* __restrict__ wo,
                            short* __restrict__ o) {
    const int z = blockIdx.y;
    const float* src = (z == 0) ? wv : (z == 1) ? wk : (z == 2) ? wq : wo;
    const float scale = (z == 2) ? (1.0f / (float)E_DIM) : 1.0f;  // fold 1/E into Wq
    size_t i = ((size_t)blockIdx.x * 256 + threadIdx.x) * 4;
    float4 f = *(const float4*)(src + i);
    short4 h;
    h.x = f2bf(f.x * scale); h.y = f2bf(f.y * scale);
    h.z = f2bf(f.z * scale); h.w = f2bf(f.w * scale);
    *(short4*)(o + (size_t)z * E_DIM * E_DIM + i) = h;
}

// ---------------------------------------------------------------------------
// Projections. Grid (128 m-tiles FAST, 6 n-tiles, 3 z) -> consecutive blocks
// share the small W tile; A streams once (L2 locality).
// z==0: V over compacted rows -> vt[b][n][i] (transposed); z==1: K compacted;
// z==2: Q full (Wq pre-scaled by 1/E).
// ---------------------------------------------------------------------------
__global__ __launch_bounds__(256, 3) void proj_kernel(
    const short* __restrict__ xv, const short* __restrict__ xk, const short* __restrict__ xq,
    const short* __restrict__ Wb, const int* __restrict__ nvp,
    short* __restrict__ vt, short* __restrict__ kb, short* __restrict__ qb)
{
    const int z  = blockIdx.z;
    const int mt = blockIdx.x;
    const int n0 = blockIdx.y * 128;

    int b = 0, lm0 = 0;
    const short* X;
    if (z == 2) {
        X = xq + (size_t)mt * 128 * E_DIM;
    } else {
        b   = mt >> 4;
        lm0 = (mt & 15) * 128;
        if (lm0 >= nvp[b]) return;
        X = ((z == 0) ? xv : xk) + ((size_t)b * S_LEN + lm0) * E_DIM;
    }
    const short* W = Wb + (size_t)z * E_DIM * E_DIM + (size_t)n0 * E_DIM;

    __shared__ short At[128 * 64];
    __shared__ short Bt[128 * 64];

    floatx4 acc[4][4];
#pragma unroll
    for (int i = 0; i < 4; ++i)
#pragma unroll
        for (int j = 0; j < 4; ++j) acc[i][j] = (floatx4){0.f, 0.f, 0.f, 0.f};

    gemm_core(X, E_DIM, W, E_DIM, E_DIM, At, Bt, acc);

    const int lane = threadIdx.x & 63, wv = threadIdx.x >> 6;
    const int lm = lane & 15, lq = lane >> 4;
    const int wm = (wv & 1) * 64, wn = (wv >> 1) * 64;

    if (z == 0) {        // vt[b][n][i]
#pragma unroll
        for (int i = 0; i < 4; ++i)
#pragma unroll
            for (int r = 0; r < 4; ++r) {
                int li = lm0 + wm + i * 16 + lq * 4 + r;
#pragma unroll
                for (int j = 0; j < 4; ++j) {
                    int n = n0 + wn + j * 16 + lm;
                    vt[((size_t)b * E_DIM + n) * S_LEN + li] = f2bf(acc[i][j][r]);
                }
            }
    } else if (z == 1) { // kb[b][i][e]
#pragma unroll
        for (int i = 0; i < 4; ++i)
#pragma unroll
            for (int r = 0; r < 4; ++r) {
                int li = lm0 + wm + i * 16 + lq * 4 + r;
#pragma unroll
                for (int j = 0; j < 4; ++j) {
                    int n = n0 + wn + j * 16 + lm;
                    kb[((size_t)b * S_LEN + li) * E_DIM + n] = f2bf(acc[i][j][r]);
                }
            }
    } else {             // qb[m][e]
#pragma unroll
        for (int i = 0; i < 4; ++i)
#pragma unroll
            for (int r = 0; r < 4; ++r) {
                int m = mt * 128 + wm + i * 16 + lq * 4 + r;
#pragma unroll
                for (int j = 0; j < 4; ++j) {
                    int n = n0 + wn + j * 16 + lm;
                    qb[(size_t)m * E_DIM + n] = f2bf(acc[i][j][r]);
                }
            }
    }
}

// ---------------------------------------------------------------------------
// S = q.k^T over compacted columns; fused exp (no max: |s|<0.5) + rowsum.
// Columns >= nv[b] (padded dups) forced to 0. P row stride stays S_LEN.
// ---------------------------------------------------------------------------
__global__ __launch_bounds__(256, 3) void score_kernel(
    const short* __restrict__ qb, const short* __restrict__ kb,
    const int* __restrict__ nv, const int* __restrict__ nvp,
    short* __restrict__ P, float* __restrict__ rowsum)
{
    const int b  = blockIdx.z;
    const int m0 = blockIdx.x * 128;
    const int n0 = blockIdx.y * 128;
    if (n0 >= nvp[b]) return;

    __shared__ short At[128 * 64];
    __shared__ short Bt[128 * 64];

    floatx4 acc[4][4];
#pragma unroll
    for (int i = 0; i < 4; ++i)
#pragma unroll
        for (int j = 0; j < 4; ++j) acc[i][j] = (floatx4){0.f, 0.f, 0.f, 0.f};

    gemm_core(qb + ((size_t)b * S_LEN + m0) * E_DIM, E_DIM,
              kb + ((size_t)b * S_LEN + n0) * E_DIM, E_DIM, E_DIM, At, Bt, acc);

    const int lane = threadIdx.x & 63, wv = threadIdx.x >> 6;
    const int lm = lane & 15, lq = lane >> 4;
    const int wm = (wv & 1) * 64, wn = (wv >> 1) * 64;
    const int nvb = nv[b];

    float rsum[4][4];
#pragma unroll
    for (int i = 0; i < 4; ++i)
#pragma unroll
        for (int r = 0; r < 4; ++r) rsum[i][r] = 0.f;

    const size_t Pbb = (size_t)b * S_LEN * S_LEN;
#pragma unroll
    for (int j = 0; j < 4; ++j) {
        int n = n0 + wn + j * 16 + lm;
        bool valid = n < nvb;
#pragma unroll
        for (int i = 0; i < 4; ++i) {
            int mbase = m0 + wm + i * 16 + lq * 4;
#pragma unroll
            for (int r = 0; r < 4; ++r) {
                float p = valid ? __expf(acc[i][j][r]) : 0.0f;
                rsum[i][r] += p;
                P[Pbb + (size_t)(mbase + r) * S_LEN + n] = f2bf(p);
            }
        }
    }
#pragma unroll
    for (int i = 0; i < 4; ++i)
#pragma unroll
        for (int r = 0; r < 4; ++r) {
            float v = rsum[i][r];
            v += __shfl_xor(v, 1);
            v += __shfl_xor(v, 2);
            v += __shfl_xor(v, 4);
            v += __shfl_xor(v, 8);
            if (lm == 0)
                atomicAdd(&rowsum[b * S_LEN + m0 + wm + i * 16 + lq * 4 + r], v);
        }
}

// ---------------------------------------------------------------------------
// O = (P.V)/rowsum over compacted K-dim (nvp[b]) -> abuf bf16.
// ---------------------------------------------------------------------------
__global__ __launch_bounds__(256, 3) void pv_kernel(
    const short* __restrict__ P, const short* __restrict__ vt,
    const float* __restrict__ rowsum, const int* __restrict__ nvp,
    short* __restrict__ abuf)
{
    const int b  = blockIdx.z;
    const int m0 = blockIdx.x * 128;
    const int n0 = blockIdx.y * 128;

    __shared__ short At[128 * 64];
    __shared__ short Bt[128 * 64];

    floatx4 acc[4][4];
#pragma unroll
    for (int i = 0; i < 4; ++i)
#pragma unroll
        for (int j = 0; j < 4; ++j) acc[i][j] = (floatx4){0.f, 0.f, 0.f, 0.f};

    gemm_core(P + (size_t)b * S_LEN * S_LEN + (size_t)m0 * S_LEN, S_LEN,
              vt + ((size_t)b * E_DIM + n0) * S_LEN, S_LEN, nvp[b], At, Bt, acc);

    const int lane = threadIdx.x & 63, wv = threadIdx.x >> 6;
    const int lm = lane & 15, lq = lane >> 4;
    const int wm = (wv & 1) * 64, wn = (wv >> 1) * 64;

#pragma unroll
    for (int i = 0; i < 4; ++i) {
        int mbase = m0 + wm + i * 16 + lq * 4;
#pragma unroll
        for (int r = 0; r < 4; ++r) {
            float inv = 1.0f / rowsum[b * S_LEN + mbase + r];
            size_t ob = ((size_t)b * S_LEN + mbase + r) * E_DIM;
#pragma unroll
            for (int j = 0; j < 4; ++j) {
                int n = n0 + wn + j * 16 + lm;
                abuf[ob + n] = f2bf(acc[i][j][r] * inv);
            }
        }
    }
}

// ---------------------------------------------------------------------------
// out[m,n] = A[m,:].Wo[n,:] + bo[n]  (fp32 out). m-fast grid.
// ---------------------------------------------------------------------------
__global__ __launch_bounds__(256, 3) void out_kernel(
    const short* __restrict__ A, const short* __restrict__ W,
    const float* __restrict__ bias, float* __restrict__ Y)
{
    const int m0 = blockIdx.x * 128;
    const int n0 = blockIdx.y * 128;

    __shared__ short At[128 * 64];
    __shared__ short Bt[128 * 64];

    floatx4 acc[4][4];
#pragma unroll
    for (int i = 0; i < 4; ++i)
#pragma unroll
        for (int j = 0; j < 4; ++j) acc[i][j] = (floatx4){0.f, 0.f, 0.f, 0.f};

    gemm_core(A + (size_t)m0 * E_DIM, E_DIM, W + (size_t)n0 * E_DIM, E_DIM,
              E_DIM, At, Bt, acc);

    const int lane = threadIdx.x & 63, wv = threadIdx.x >> 6;
    const int lm = lane & 15, lq = lane >> 4;
    const int wm = (wv & 1) * 64, wn = (wv >> 1) * 64;

#pragma unroll
    for (int j = 0; j < 4; ++j) {
        int n = n0 + wn + j * 16 + lm;
        float bv = bias[n];
#pragma unroll
        for (int i = 0; i < 4; ++i)
#pragma unroll
            for (int r = 0; r < 4; ++r) {
                int m = m0 + wm + i * 16 + lq * 4 + r;
                Y[(size_t)m * E_DIM + n] = acc[i][j][r] + bv;
            }
    }
}

// ---------------------------------------------------------------------------
extern "C" void kernel_launch(void* const* d_in, const int* in_sizes, int n_in,
                              void* d_out, int out_size, void* d_ws, size_t ws_size,
                              hipStream_t stream) {
    const float* value = (const float*)d_in[0];
    const float* key   = (const float*)d_in[1];
    const float* query = (const float*)d_in[2];
    const int*   mask  = (const int*)d_in[3];
    const float* Wv    = (const float*)d_in[4];
    const float* Wk    = (const float*)d_in[5];
    const float* Wq    = (const float*)d_in[6];
    const float* Wo    = (const float*)d_in[7];
    const float* bo    = (const float*)d_in[8];
    float* out = (float*)d_out;

    const size_t WN  = (size_t)E_DIM * E_DIM;            // 589824
    const size_t ACT = (size_t)BATCH * S_LEN * E_DIM;    // 12582912

    // ws layout (shorts). P overlays dead xv/xk; abuf overlays dead qb;
    // jidx overlays qb head (dead until proj).
    short* Wb  = (short*)d_ws;         // 4 weights: Wv,Wk,Wq(scaled),Wo
    short* xv  = Wb + 4 * WN;
    short* xk  = xv + ACT;
    short* xq  = xk + ACT;
    short* vt  = xq + ACT;
    short* kb  = vt + ACT;
    short* qb  = kb + ACT;
    float* rowsum = (float*)(qb + ACT);                  // 16384 floats
    int*   nv  = (int*)(rowsum + (size_t)BATCH * S_LEN); // 8 ints
    int*   nvp = nv + BATCH;                             // 8 ints
    int*   jidx = (int*)qb;            // 16384 ints, consumed before proj
    short* P    = xv;                  // 8*2048*2048 <= 3*ACT
    short* abuf = qb;                  // == ACT

    hipMemsetAsync(rowsum, 0, (size_t)BATCH * S_LEN * sizeof(float), stream);

    mask_scan<<<BATCH, 256, 0, stream>>>(mask, jidx, nv, nvp);
    convert_wts<<<dim3(576, 4), 256, 0, stream>>>(Wv, Wk, Wq, Wo, Wb);
    convert_gather<<<dim3(512, 3, 8), 256, 0, stream>>>(value, key, query,
                                                        jidx, nvp, xv, xk, xq);

    proj_kernel<<<dim3(128, 6, 3), 256, 0, stream>>>(xv, xk, xq, Wb, nvp,
                                                     vt, kb, qb);

    score_kernel<<<dim3(16, 16, 8), 256, 0, stream>>>(qb, kb, nv, nvp, P, rowsum);

    pv_kernel<<<dim3(16, 6, 8), 256, 0, stream>>>(P, vt, rowsum, nvp, abuf);

    out_kernel<<<dim3(128, 6), 256, 0, stream>>>(abuf, Wb + 3 * WN, bo, out);
}